// Round 7
// baseline (548.689 us; speedup 1.0000x reference)
//
#include <hip/hip_runtime.h>
#include <hip/hip_bf16.h>

typedef short bf16x8 __attribute__((ext_vector_type(8)));
typedef float f32x4 __attribute__((ext_vector_type(4)));

#define MFMA_BF16 __builtin_amdgcn_mfma_f32_16x16x32_bf16
#define BARRIER() asm volatile("s_barrier" ::: "memory")

__device__ __forceinline__ float bf2f(short u) {
  return __uint_as_float(((unsigned int)(unsigned short)u) << 16);
}
__device__ __forceinline__ unsigned short f2bf(float f) {
  unsigned int u = __float_as_uint(f);
  u = u + 0x7FFFu + ((u >> 16) & 1u);   // RNE
  return (unsigned short)(u >> 16);
}

// ---------------- convert fp32 -> bf16 ----------------
__global__ __launch_bounds__(256)
void cvt_f32_bf16(const float* __restrict__ in, unsigned short* __restrict__ out, int n8) {
  int i = blockIdx.x * 256 + threadIdx.x;
  if (i >= n8) return;
  const float4* p = (const float4*)in + (size_t)i * 2;
  float4 a = p[0], b = p[1];
  bf16x8 o;
  o[0] = (short)f2bf(a.x); o[1] = (short)f2bf(a.y); o[2] = (short)f2bf(a.z); o[3] = (short)f2bf(a.w);
  o[4] = (short)f2bf(b.x); o[5] = (short)f2bf(b.y); o[6] = (short)f2bf(b.z); o[7] = (short)f2bf(b.w);
  *((bf16x8*)out + i) = o;
}

// ---------------- transpose + convert: in[K][N] f32 -> out[N][K] bf16 ----------------
__global__ __launch_bounds__(256)
void tcvt(const float* __restrict__ in, unsigned short* __restrict__ out, int K, int N) {
  __shared__ float t[32][33];
  int n0 = blockIdx.x * 32, k0 = blockIdx.y * 32;
  int tx = threadIdx.x & 31, ty = threadIdx.x >> 5;
#pragma unroll
  for (int j = 0; j < 4; ++j)
    t[ty + 8 * j][tx] = in[(size_t)(k0 + ty + 8 * j) * N + n0 + tx];
  __syncthreads();
#pragma unroll
  for (int j = 0; j < 4; ++j)
    out[(size_t)(n0 + ty + 8 * j) * K + k0 + tx] = f2bf(t[tx][ty + 8 * j]);
}

// ====== persistent 4-slot-ring bf16 MFMA GEMM, 2 blocks/CU: C = A(32768xK) @ Bt(NxK)^T ======
// BM=128, BN=128, BK=32. grid = 512 blocks (2/CU): stripe = bid&255 (128-row A stripe),
// half = bid>>8 walks bn in [half*NTILES, (half+1)*NTILES). 256 thr = 4 waves (2M x 2N),
// wave tile 64x64 -> 16 MFMA + 8 ds_read_b128 per BK=32 phase.
// LDS: 4 slots x 8192 shorts (A[128][32] @0, B[128][32] @4096), spare @32768 (1024 sh/wave).
// Phase p reads slot p&3; issues 4 loads for phase p+3 into slot (p+3)&3 (safe: all waves
// passed barrier of p => done reading that slot at p-1). Steady wait vmcnt(8); tail 4, 0.
// Row swizzle: byte-col ^= ((row>>1)&3)<<4 applied at global source + LDS read.
template <int EPI, int NTILES>
__global__ __launch_bounds__(256, 2)
void gemmP2(const unsigned short* __restrict__ A, const unsigned short* __restrict__ Bt,
            void* __restrict__ Cout, const float* __restrict__ bias,
            int N, int K, int eluCols) {
  __shared__ __align__(16) unsigned short lds[36864];   // 72 KiB
  const int tid = threadIdx.x;
  const int wid = tid >> 6, lane = tid & 63;
  const int wr = wid >> 1, wc = wid & 1;
  const int fr = lane & 15, fq = lane >> 4;
  const int stripe = blockIdx.x & 255;
  const int half = blockIdx.x >> 8;
  const int rowA0 = stripe << 7;
  const int bn0 = half * NTILES;

  const int sr  = tid >> 2;                             // staging row 0..63 per issue
  const int scb = (tid & 3) << 4;                       // staging byte-col
  const int co  = (scb ^ (((sr >> 1) & 3) << 4)) >> 1;  // pre-swizzled src col (shorts)
  const int stW = wid << 9;                             // wave LDS offset (shorts)

  int aOff[4], bOff[4];
#pragma unroll
  for (int m = 0; m < 4; ++m) {
    int row = (wr << 6) + (m << 4) + fr;
    aOff[m] = (row << 5) + (((fq << 4) ^ (((row >> 1) & 3) << 4)) >> 1);
  }
#pragma unroll
  for (int n = 0; n < 4; ++n) {
    int row = (wc << 6) + (n << 4) + fr;
    bOff[n] = 4096 + (row << 5) + (((fq << 4) ^ (((row >> 1) & 3) << 4)) >> 1);
  }

  auto issueA = [&](int slotS, int j, int kcol) {
    const unsigned short* src = A + (size_t)(rowA0 + (j << 6) + sr) * K + kcol + co;
    __builtin_amdgcn_global_load_lds(
        (const __attribute__((address_space(1))) void*)src,
        (__attribute__((address_space(3))) void*)(lds + slotS + (j << 11) + stW),
        16, 0, 0);
  };
  auto issueB = [&](int slotS, int j, int kcol, int brow0) {
    const unsigned short* src = Bt + (size_t)(brow0 + (j << 6) + sr) * K + kcol + co;
    __builtin_amdgcn_global_load_lds(
        (const __attribute__((address_space(1))) void*)src,
        (__attribute__((address_space(3))) void*)(lds + slotS + 4096 + (j << 11) + stW),
        16, 0, 0);
  };

  const int TOTG = NTILES * 24;
  // prologue: stage phases 0,1,2 (12 issues)
#pragma unroll
  for (int g = 0; g < 3; ++g) {
    int kcol = g << 5;
    int ss = g << 13;
    issueA(ss, 0, kcol); issueA(ss, 1, kcol);
    issueB(ss, 0, kcol, bn0 << 7); issueB(ss, 1, kcol, bn0 << 7);
  }

  int G = 0, ktn = 3, bnn = bn0;
  const size_t ldc = (size_t)N;

  for (int T = 0; T < NTILES; ++T) {
    f32x4 acc[4][4];
#pragma unroll
    for (int m = 0; m < 4; ++m)
#pragma unroll
      for (int n = 0; n < 4; ++n) acc[m][n] = (f32x4)(0.f);

    for (int kt = 0; kt < 24; ++kt) {
      if (G < TOTG - 2)       { asm volatile("s_waitcnt vmcnt(8)" ::: "memory"); }
      else if (G == TOTG - 2) { asm volatile("s_waitcnt vmcnt(4)" ::: "memory"); }
      else                    { asm volatile("s_waitcnt vmcnt(0)" ::: "memory"); }
      BARRIER();
      const unsigned short* sl = lds + ((G & 3) << 13);
      bf16x8 av[4], bw[4];
#pragma unroll
      for (int m = 0; m < 4; ++m) av[m] = *(const bf16x8*)(sl + aOff[m]);
#pragma unroll
      for (int n = 0; n < 4; ++n) bw[n] = *(const bf16x8*)(sl + bOff[n]);
      if (G + 3 < TOTG) {
        int ss = ((G + 3) & 3) << 13;
        int kcol = ktn << 5;
        issueA(ss, 0, kcol); issueA(ss, 1, kcol);
        issueB(ss, 0, kcol, bnn << 7); issueB(ss, 1, kcol, bnn << 7);
      }
      __builtin_amdgcn_s_setprio(1);
#pragma unroll
      for (int m = 0; m < 4; ++m)
#pragma unroll
        for (int n = 0; n < 4; ++n)
          acc[m][n] = MFMA_BF16(av[m], bw[n], acc[m][n], 0, 0, 0);
      __builtin_amdgcn_s_setprio(0);
      ++G;
      if (++ktn == 24) { ktn = 0; ++bnn; }
    }

    // ---- epilogue for tile T (wave-private spare LDS; no cross-wave barrier) ----
    {
      const int bnT = bn0 + T;
      const int colBase = (bnT << 7) + (wc << 6);
      const size_t gr0 = (size_t)rowA0 + ((size_t)wr << 6);
      if (EPI == 0) {
        unsigned short* sp = lds + 32768 + (wid << 10);   // [16 rows][64 cols] bf16
        unsigned short* Cb = (unsigned short*)Cout;
#pragma unroll
        for (int m = 0; m < 4; ++m) {
#pragma unroll
          for (int n = 0; n < 4; ++n) {
            int col = colBase + (n << 4) + fr;
            bool elu = col < eluCols;
#pragma unroll
            for (int r = 0; r < 4; ++r) {
              float x = acc[m][n][r];
              if (elu) x = x > 0.f ? x + 1.f : __expf(x);   // elu(x)+1
              sp[(((fq << 2) + r) << 6) + (n << 4) + fr] = f2bf(x);
            }
          }
          asm volatile("s_waitcnt lgkmcnt(0)" ::: "memory");
          __builtin_amdgcn_sched_barrier(0);
          int row = lane >> 2, cg = lane & 3;
          bf16x8 v0 = *(const bf16x8*)(sp + (row << 6) + (cg << 4));
          bf16x8 v1 = *(const bf16x8*)(sp + (row << 6) + (cg << 4) + 8);
          unsigned short* dst = Cb + (gr0 + (m << 4) + row) * ldc + colBase + (cg << 4);
          *(bf16x8*)dst = v0;
          *(bf16x8*)(dst + 8) = v1;
          asm volatile("s_waitcnt lgkmcnt(0)" ::: "memory");
          __builtin_amdgcn_sched_barrier(0);
        }
      } else {
        float* spf = (float*)(lds + 32768 + (wid << 10));  // [16 rows][32 cols] f32
        float* Cf = (float*)Cout;
        float bv[4];
#pragma unroll
        for (int n = 0; n < 4; ++n) bv[n] = bias[colBase + (n << 4) + fr];
#pragma unroll
        for (int m = 0; m < 4; ++m) {
#pragma unroll
          for (int nh = 0; nh < 2; ++nh) {
#pragma unroll
            for (int nn = 0; nn < 2; ++nn) {
              int n = nh * 2 + nn;
#pragma unroll
              for (int r = 0; r < 4; ++r)
                spf[(((fq << 2) + r) << 5) + (nn << 4) + fr] = acc[m][n][r] + bv[n];
            }
            asm volatile("s_waitcnt lgkmcnt(0)" ::: "memory");
            __builtin_amdgcn_sched_barrier(0);
            int row = lane >> 2, cg = lane & 3;
            f32x4 v0 = *(const f32x4*)(spf + (row << 5) + (cg << 3));
            f32x4 v1 = *(const f32x4*)(spf + (row << 5) + (cg << 3) + 4);
            float* dst = Cf + (gr0 + (m << 4) + row) * ldc + colBase + (nh << 5) + (cg << 3);
            *(f32x4*)dst = v0;
            *(f32x4*)(dst + 4) = v1;
            asm volatile("s_waitcnt lgkmcnt(0)" ::: "memory");
            __builtin_amdgcn_sched_barrier(0);
          }
        }
      }
    }
  }
}

// ---------------- kv[b,h,d,e] = sum_s k[s,d]*v[s,e]; ksum[b,h,d] = sum_s k[s,d] ----------------
__global__ __launch_bounds__(256)
void kv_accum(const unsigned short* __restrict__ qkv, float* __restrict__ kv_out,
              float* __restrict__ ksum) {
  const int bh = blockIdx.x;
  const int b = bh / 12, h = bh - b * 12;
  const int s0 = blockIdx.y * 512;
  __shared__ __align__(16) float ks[128][64];
  __shared__ __align__(16) float vs[128][64];
  const int td = threadIdx.x >> 4, te = threadIdx.x & 15;
  float acc[4][4] = {};
  float ksl[4] = {};
  for (int c = 0; c < 4; ++c) {
    const size_t rowbase = (size_t)(b * 4096 + s0 + c * 128) * 2304;
    const unsigned short* kg = qkv + rowbase + 768 + h * 64;
    const unsigned short* vg = qkv + rowbase + 1536 + h * 64;
    for (int i = threadIdx.x; i < 128 * 8; i += 256) {
      int s = i >> 3, dc = (i & 7) << 3;
      bf16x8 k8 = *(const bf16x8*)(kg + (size_t)s * 2304 + dc);
      bf16x8 v8 = *(const bf16x8*)(vg + (size_t)s * 2304 + dc);
#pragma unroll
      for (int j = 0; j < 8; ++j) {
        ks[s][dc + j] = bf2f(k8[j]);
        vs[s][dc + j] = bf2f(v8[j]);
      }
    }
    __syncthreads();
#pragma unroll 4
    for (int s = 0; s < 128; ++s) {
      f32x4 ka = *(const f32x4*)&ks[s][td * 4];
      f32x4 va = *(const f32x4*)&vs[s][te * 4];
#pragma unroll
      for (int i = 0; i < 4; ++i) {
        ksl[i] += ka[i];
#pragma unroll
        for (int j = 0; j < 4; ++j) acc[i][j] += ka[i] * va[j];
      }
    }
    __syncthreads();
  }
  float* kvp = kv_out + ((size_t)bh * 64 + td * 4) * 64 + te * 4;
#pragma unroll
  for (int i = 0; i < 4; ++i)
#pragma unroll
    for (int j = 0; j < 4; ++j) atomicAdd(&kvp[(size_t)i * 64 + j], acc[i][j]);
  if (te == 0) {
#pragma unroll
    for (int i = 0; i < 4; ++i) atomicAdd(&ksum[bh * 64 + td * 4 + i], ksl[i]);
  }
}

// ---------------- attn[b,s,h*64+e] = z * sum_d q[s,d]*kv[d,e];  z = 1/sum_d q[s,d]*ksum[d] ----------------
__global__ __launch_bounds__(256)
void attn_out(const unsigned short* __restrict__ qkv, const float* __restrict__ kv,
              const float* __restrict__ ksum, unsigned short* __restrict__ attn) {
  const int bh = blockIdx.x;
  const int b = bh / 12, h = bh - b * 12;
  const int s0 = blockIdx.y * 64;
  __shared__ __align__(16) float kvs[64][64];
  __shared__ float kss[64];
  {
    const float4* kvg = (const float4*)(kv + (size_t)bh * 4096);
    float4* kvl = (float4*)&kvs[0][0];
    for (int i = threadIdx.x; i < 1024; i += 256) kvl[i] = kvg[i];
    if (threadIdx.x < 64) kss[threadIdx.x] = ksum[bh * 64 + threadIdx.x];
  }
  __syncthreads();
  const int tr = threadIdx.x >> 2;
  const int te = threadIdx.x & 3;
  const int s = s0 + tr;
  const unsigned short* qg = qkv + (size_t)(b * 4096 + s) * 2304 + h * 64;
  bf16x8 q8[8];
#pragma unroll
  for (int c = 0; c < 8; ++c) q8[c] = *(const bf16x8*)(qg + c * 8);
  float acc[16] = {};
  float zz = 0.f;
#pragma unroll
  for (int c = 0; c < 8; ++c) {
#pragma unroll
    for (int j = 0; j < 8; ++j) {
      const int d = c * 8 + j;
      const float qd = bf2f(q8[c][j]);
      zz += qd * kss[d];
      const f32x4* kvr = (const f32x4*)&kvs[d][te * 16];
#pragma unroll
      for (int q4 = 0; q4 < 4; ++q4) {
        f32x4 kk = kvr[q4];
        acc[q4 * 4 + 0] += qd * kk[0];
        acc[q4 * 4 + 1] += qd * kk[1];
        acc[q4 * 4 + 2] += qd * kk[2];
        acc[q4 * 4 + 3] += qd * kk[3];
      }
    }
  }
  const float z = 1.f / zz;
  bf16x8 o0, o1;
#pragma unroll
  for (int j = 0; j < 8; ++j) o0[j] = (short)f2bf(acc[j] * z);
#pragma unroll
  for (int j = 0; j < 8; ++j) o1[j] = (short)f2bf(acc[8 + j] * z);
  unsigned short* og = attn + (size_t)(b * 4096 + s) * 768 + h * 64 + te * 16;
  *(bf16x8*)og = o0;
  *(bf16x8*)(og + 8) = o1;
}

extern "C" void kernel_launch(void* const* d_in, const int* in_sizes, int n_in,
                              void* d_out, int out_size, void* d_ws, size_t ws_size,
                              hipStream_t stream) {
  const float* x      = (const float*)d_in[0];
  const float* w_qkv  = (const float*)d_in[1];
  const float* w_proj = (const float*)d_in[2];
  const float* b_proj = (const float*)d_in[3];
  const int B = 8, N = 4096, C = 768, H = 12, D = 64;
  const int M = B * N;      // 32768
  const int N1 = 3 * C;     // 2304

  char* ws = (char*)d_ws;
  unsigned short* xb     = (unsigned short*)(ws);               // 50,331,648 B (reused for attn out)
  unsigned short* wqkvT  = (unsigned short*)(ws + 50331648);    //  3,538,944 B
  unsigned short* wprojT = (unsigned short*)(ws + 53870592);    //  1,179,648 B
  float*          ksum   = (float*)(ws + 55050240);             //     24,576 B
  unsigned short* qkvb   = (unsigned short*)(ws + 55074816);    // 150,994,944 B

  float* out_main = (float*)d_out;
  float* kv_out   = out_main + (size_t)M * C;   // kv output: (B,H,D,D) f32

  hipMemsetAsync(kv_out, 0, (size_t)B * H * D * D * sizeof(float), stream);
  hipMemsetAsync(ksum, 0, (size_t)B * H * D * sizeof(float), stream);

  cvt_f32_bf16<<<(M * C / 8 + 255) / 256, 256, 0, stream>>>(x, xb, M * C / 8);
  tcvt<<<dim3(N1 / 32, C / 32), 256, 0, stream>>>(w_qkv, wqkvT, C, N1);
  tcvt<<<dim3(C / 32, C / 32), 256, 0, stream>>>(w_proj, wprojT, C, C);

  // qkv = x @ w_qkv (elu+1 on q,k cols), bf16 out. persistent 2/CU: 512 blocks x 9 bn-tiles
  gemmP2<0, 9><<<512, 256, 0, stream>>>(xb, wqkvT, qkvb, nullptr, N1, C, 2 * C);

  // global kv + ksum accumulation
  kv_accum<<<dim3(B * H, N / 512), 256, 0, stream>>>(qkvb, kv_out, ksum);

  // out_attn = (q @ kv) * z, bf16 into xb
  attn_out<<<dim3(B * H, N / 64), 256, 0, stream>>>(qkvb, kv_out, ksum, xb);

  // out = attn @ w_proj + b_proj, fp32. persistent 2/CU: 512 blocks x 3 bn-tiles
  gemmP2<1, 3><<<512, 256, 0, stream>>>(xb, wprojT, d_out, b_proj, C, C, 0);
}